// Round 8
// baseline (109.967 us; speedup 1.0000x reference)
//
#include <hip/hip_runtime.h>
#include <math.h>

// ---------------------------------------------------------------------------
// Fused MoE top-2 router, MI355X (gfx950) — round 8.
// R7 architecture (resident-W, single barrier, register-prefetched x) with
// the staging-loop OOB bug fixed: 8192 float4 slots / 512 threads = 16 per
// thread (R7 had 64 -> wrote 4x past wres + read W OOB -> abort).
// Main loop is barrier-free: x prefetched a full half-chunk chain ahead
// (~1024cy > 900cy HBM latency), W via conflict-clean ds_read_b128.
// 512-thr blocks, launch_bounds(512,2) caps VGPR at 256 (live ~190).
// Deterministic slab partials + pass2 epilogue (bitwise-validated R4-R6).
// ---------------------------------------------------------------------------

#define NT 8192
#define ND 4096
#define NE 64
#define BK 64             // k floats per chunk
#define SECK 512          // k floats per resident section (kq=8)
#define SLAB_OFF 512      // ws[0..129] scalars; slabs after

__device__ __forceinline__ void gload16(const float* g, float* l) {
    __builtin_amdgcn_global_load_lds(
        (const __attribute__((address_space(1))) void*)g,
        (__attribute__((address_space(3))) void*)l, 16, 0, 0);
}

#define LOADX(dst, off)                                                      \
    {                                                                        \
        _Pragma("unroll")                                                    \
        for (int t = 0; t < 8; t++)                                          \
            dst[t] = *reinterpret_cast<const float4*>(                       \
                xp + (size_t)t * ND + (off));                                \
    }

#define COMP(xv, wptr, wstride)                                              \
    {                                                                        \
        float4 wv[8];                                                        \
        _Pragma("unroll")                                                    \
        for (int e = 0; e < 8; e++)                                          \
            wv[e] = *reinterpret_cast<const float4*>((wptr) + e * (wstride));\
        _Pragma("unroll")                                                    \
        for (int e = 0; e < 8; e++) {                                        \
            _Pragma("unroll")                                                \
            for (int t = 0; t < 8; t++) {                                    \
                float a = acc[t][e];                                         \
                a = fmaf(xv[t].x, wv[e].x, a);                               \
                a = fmaf(xv[t].y, wv[e].y, a);                               \
                a = fmaf(xv[t].z, wv[e].z, a);                               \
                a = fmaf(xv[t].w, wv[e].w, a);                               \
                acc[t][e] = a;                                               \
            }                                                                \
        }                                                                    \
    }

#define KREDUCE_AND_SLAB()                                                   \
    {                                                                        \
        _Pragma("unroll")                                                    \
        for (int t = 0; t < 8; t++)                                          \
            _Pragma("unroll")                                                \
            for (int e = 0; e < 8; e++) {                                    \
                float v = acc[t][e];                                         \
                v += __shfl_xor(v, 1);                                       \
                v += __shfl_xor(v, 2);                                       \
                v += __shfl_xor(v, 4);                                       \
                acc[t][e] = v;                                               \
            }                                                                \
        _Pragma("unroll")                                                    \
        for (int t = 0; t < 8; t++) {                                        \
            if (ks == t) {                                                   \
                *reinterpret_cast<float4*>(slab + (size_t)t * NE + eg * 8) = \
                    make_float4(acc[t][0], acc[t][1], acc[t][2], acc[t][3]); \
                *reinterpret_cast<float4*>(slab + (size_t)t * NE + eg * 8 + 4) = \
                    make_float4(acc[t][4], acc[t][5], acc[t][6], acc[t][7]); \
            }                                                                \
        }                                                                    \
    }

// ---- primary: resident-W, barrier-free main loop, kq = 8 -----------------
__global__ __launch_bounds__(512, 2)
void pass1_res(const float* __restrict__ x, const float* __restrict__ W,
               float* __restrict__ ws)
{
    __shared__ float wres[NE * SECK];   // 128 KiB, whole K-section of W

    const int tid  = threadIdx.x;
    const int wave = tid >> 6;
    const int lane = tid & 63;
    const int eg   = lane >> 3;          // expert octet 0..7
    const int ks   = lane & 7;           // k slice 0..7 (x 4 floats)

    const int bq   = blockIdx.x >> 7;    // section 0..7
    const int tb   = blockIdx.x & 127;   // token block (64 tokens)
    const int tok0 = tb * 64 + wave * 8;
    const int k0   = bq * SECK;

    float acc[8][8];
    #pragma unroll
    for (int t = 0; t < 8; t++)
        #pragma unroll
        for (int e = 0; e < 8; e++) acc[t][e] = 0.f;

    // stage the whole W section once: 8192 float4 slots / 512 thr = 16 each
    #pragma unroll
    for (int r = 0; r < 16; r++) {
        int s = r * 512 + tid;            // 0..8191
        gload16(W + (size_t)(s >> 7) * ND + k0 + (s & 127) * 4,
                &wres[s << 2]);
    }

    const float* xp = x + (size_t)tok0 * ND + k0 + ks * 4;
    float4 xa[8], xb[8];
    LOADX(xa, 0);                        // overlaps the staging drain
    __syncthreads();                     // the ONLY barrier

    const float* wsec = &wres[(eg * 8) * SECK + ks * 4];
    #pragma unroll 1
    for (int c = 0; c < SECK / BK; ++c) {          // 8 chunks, no barriers
        LOADX(xb, c * BK + 32);                    // used ~1024 cy later
        COMP(xa, wsec + c * BK, SECK);
        if (c + 1 < SECK / BK) LOADX(xa, (c + 1) * BK);
        COMP(xb, wsec + c * BK + 32, SECK);
    }

    float* slab = ws + SLAB_OFF + ((size_t)bq * NT + tok0) * NE;
    KREDUCE_AND_SLAB();
}

// ---- fallback: R6 double-buffered W (used only if ws too small) ----------
__global__ __launch_bounds__(256, 2)
void pass1_dbuf(const float* __restrict__ x, const float* __restrict__ W,
                float* __restrict__ ws, int kq_bits, int nchunk)
{
    __shared__ float wbuf[2][NE * BK];

    const int tid  = threadIdx.x;
    const int wave = tid >> 6;
    const int lane = tid & 63;
    const int eg   = lane >> 3;
    const int ks   = lane & 7;

    const int bq   = blockIdx.x >> 8;
    const int tb   = blockIdx.x & 255;
    const int tok0 = tb * 32 + wave * 8;
    const int k0   = bq * (ND >> kq_bits);

    float acc[8][8];
    #pragma unroll
    for (int t = 0; t < 8; t++)
        #pragma unroll
        for (int e = 0; e < 8; e++) acc[t][e] = 0.f;

    const float* xp = x + (size_t)tok0 * ND + k0 + ks * 4;

    #pragma unroll
    for (int r = 0; r < 4; r++) {
        int s = r * 256 + tid;
        gload16(W + (size_t)(s >> 4) * ND + k0 + (s & 15) * 4, &wbuf[0][s << 2]);
    }
    float4 xa[8], xb[8];
    LOADX(xa, 0);
    __syncthreads();

    #pragma unroll 1
    for (int c = 0; c < nchunk; ++c) {
        const int b = c & 1;
        if (c + 1 < nchunk) {
            const int koff = k0 + (c + 1) * BK;
            #pragma unroll
            for (int r = 0; r < 4; r++) {
                int s = r * 256 + tid;
                gload16(W + (size_t)(s >> 4) * ND + koff + (s & 15) * 4,
                        &wbuf[b ^ 1][s << 2]);
            }
        }
        LOADX(xb, c * BK + 32);
        COMP(xa, &wbuf[b][(eg * 8) * BK + ks * 4], BK);
        if (c + 1 < nchunk) LOADX(xa, (c + 1) * BK);
        COMP(xb, &wbuf[b][(eg * 8) * BK + 32 + ks * 4], BK);
        __syncthreads();
    }

    float* slab = ws + SLAB_OFF + ((size_t)bq * NT + tok0) * NE;
    KREDUCE_AND_SLAB();
}

__global__ __launch_bounds__(128)
void pass2(float* __restrict__ ws, float* __restrict__ out, int kq)
{
    __shared__ float imp_s[NE];
    __shared__ float load_s[NE];
    const int tid  = threadIdx.x;
    const int lane = tid & 63;
    if (tid < NE) { imp_s[tid] = 0.f; load_s[tid] = 0.f; }
    __syncthreads();

    const int tok = blockIdx.x * 128 + tid;
    float lgv[NE];
    {
        const float* p0 = ws + SLAB_OFF + (size_t)tok * NE;
        #pragma unroll
        for (int e4 = 0; e4 < 16; e4++) {
            float4 v = *reinterpret_cast<const float4*>(p0 + e4 * 4);
            lgv[e4*4+0] = v.x; lgv[e4*4+1] = v.y;
            lgv[e4*4+2] = v.z; lgv[e4*4+3] = v.w;
        }
        for (int q = 1; q < kq; q++) {
            const float* pq = ws + SLAB_OFF + ((size_t)q * NT + tok) * NE;
            #pragma unroll
            for (int e4 = 0; e4 < 16; e4++) {
                float4 v = *reinterpret_cast<const float4*>(pq + e4 * 4);
                lgv[e4*4+0] += v.x; lgv[e4*4+1] += v.y;
                lgv[e4*4+2] += v.z; lgv[e4*4+3] += v.w;
            }
        }
    }

    float m = -3.0e38f;
    #pragma unroll
    for (int e = 0; e < NE; e++) m = fmaxf(m, lgv[e]);
    float se = 0.f, ssum = 0.f;
    #pragma unroll
    for (int e = 0; e < NE; e++) { ssum += lgv[e]; se += __expf(lgv[e] - m); }
    const float lse = m + __logf(se);
    const float inv = 1.f / se;

    #pragma unroll
    for (int e = 0; e < NE; e++) lgv[e] = __expf(lgv[e] - m) * inv;

    float v1 = -3.0e38f, v2 = -3.0e38f;
    int   i1 = 0, i2 = 0;
    #pragma unroll
    for (int e = 0; e < NE; e++) {
        const float v = lgv[e];
        if (v > v1)      { v2 = v1; i2 = i1; v1 = v; i1 = e; }
        else if (v > v2) { v2 = v;  i2 = e; }
    }
    const float dn = fmaxf(v1 + v2, 1e-9f);

    out[2 * tok]              = (float)i1;
    out[2 * tok + 1]          = (float)i2;
    out[2 * NT + 2 * tok]     = v1 / dn;
    out[2 * NT + 2 * tok + 1] = v2 / dn;
    atomicAdd(&load_s[i1], 1.0f);

    float zv = lse * lse, sv = ssum;
    #pragma unroll
    for (int mk = 1; mk < 64; mk <<= 1) {
        zv += __shfl_xor(zv, mk);
        sv += __shfl_xor(sv, mk);
    }
    if (lane == 0) { atomicAdd(&ws[128], zv); atomicAdd(&ws[129], sv); }

    float impacc = 0.f;
    #pragma unroll
    for (int e = 0; e < NE; e++) {
        float v = lgv[e];
        #pragma unroll
        for (int mk = 1; mk < 64; mk <<= 1) v += __shfl_xor(v, mk);
        if (lane == e) impacc = v;
    }
    atomicAdd(&imp_s[lane], impacc);

    __syncthreads();
    if (tid < NE) {
        atomicAdd(&ws[tid], imp_s[tid]);
        atomicAdd(&ws[NE + tid], load_s[tid]);
    }
}

__global__ void finalize(const float* __restrict__ ws, float* __restrict__ out)
{
    const int l = threadIdx.x;   // one wave
    const float imp = ws[l];
    const float ld  = ws[NE + l];
    float is = imp, ls = ld;
    #pragma unroll
    for (int mk = 1; mk < 64; mk <<= 1) { is += __shfl_xor(is, mk); ls += __shfl_xor(ls, mk); }
    float v = (imp / fmaxf(is, 1e-9f)) * (ld / fmaxf(ls, 1e-9f));
    #pragma unroll
    for (int mk = 1; mk < 64; mk <<= 1) v += __shfl_xor(v, mk);
    if (l == 0) {
        out[4 * NT]     = (ws[128] / (float)NT) * 0.001f;        // router_z_loss
        out[4 * NT + 1] = v * (float)(NE * NE) * 0.01f;          // load_balance_loss
        out[4 * NT + 2] = ws[129] / (float)((size_t)NT * NE);    // logits_mean
    }
}

extern "C" void kernel_launch(void* const* d_in, const int* in_sizes, int n_in,
                              void* d_out, int out_size, void* d_ws, size_t ws_size,
                              hipStream_t stream) {
    const float* x = (const float*)d_in[0];
    const float* W = (const float*)d_in[1];
    float* out = (float*)d_out;
    float* ws  = (float*)d_ws;

    hipMemsetAsync(ws, 0, 130 * sizeof(float), stream);

    if (ws_size >= (SLAB_OFF + 8ull * NT * NE) * 4) {
        // resident-W path: 8 sections x 128 token-blocks, barrier-free loop
        hipLaunchKernelGGL(pass1_res, dim3(8 * (NT / 64)), dim3(512), 0, stream,
                           x, W, ws);
        hipLaunchKernelGGL(pass2, dim3(NT / 128), dim3(128), 0, stream, ws, out, 8);
    } else {
        int kq_bits = 2;
        if (ws_size < (SLAB_OFF + 4ull * NT * NE) * 4) kq_bits = 1;
        if (ws_size < (SLAB_OFF + 2ull * NT * NE) * 4) kq_bits = 0;
        const int kq = 1 << kq_bits;
        const int nchunk = (ND >> kq_bits) / BK;
        hipLaunchKernelGGL(pass1_dbuf, dim3(256 * kq), dim3(256), 0, stream,
                           x, W, ws, kq_bits, nchunk);
        hipLaunchKernelGGL(pass2, dim3(NT / 128), dim3(128), 0, stream, ws, out, kq);
    }
    hipLaunchKernelGGL(finalize, dim3(1), dim3(64), 0, stream, ws, out);
}